// Round 1
// baseline (590.183 us; speedup 1.0000x reference)
//
#include <hip/hip_runtime.h>
#include <hip/hip_bf16.h>
#include <math.h>

#define NROWS 8192
#define INDIM 768
#define TD    72
#define DM    24
#define MKEYS 8192
#define KSEL  32
#define HN    256
#define CAND  128

#define TWO_PI_F 6.283185307179586f

__device__ __forceinline__ float gelu_exact(float v){
  return 0.5f * v * (1.0f + erff(v * 0.7071067811865476f));
}

// ---------------------------------------------------------------------------
// K1: y = x@W_in.T + b_in ; LN(72); GELU; ricci einsum + mean over 3 -> q(24)
// block: 256 threads, 16 rows. thread = (r2 = t>>4, ks = (t>>3)&1, u = t&7)
// each (r2,u) computes 9 outputs o = u+8j over half the k-range, combined via shfl.
// ---------------------------------------------------------------------------
__global__ __launch_bounds__(256) void k1_encode(
    const float* __restrict__ x, const float* __restrict__ Wi,
    const float* __restrict__ bi, const float* __restrict__ gi,
    const float* __restrict__ bbi, const float* __restrict__ ricci,
    float* __restrict__ qvec, float* __restrict__ qnorm)
{
  __shared__ float xs[16][132];
  __shared__ float Ws[TD][132];
  __shared__ float zs[16][73];
  __shared__ float zb[16][25];
  const int t = threadIdx.x;
  const int r2 = t >> 4, ks = (t >> 3) & 1, u = t & 7;
  const int row0 = blockIdx.x * 16;

  float acc[9];
#pragma unroll
  for (int j = 0; j < 9; j++) acc[j] = 0.f;

  for (int kc = 0; kc < 6; kc++) {
    __syncthreads();
#pragma unroll
    for (int i = 0; i < 2; i++) {            // x chunk: 16x128 = 512 float4
      int idx = t + 256 * i;
      int rr = idx >> 5, kk = (idx & 31) << 2;
      *(float4*)&xs[rr][kk] = *(const float4*)&x[(size_t)(row0 + rr) * INDIM + kc * 128 + kk];
    }
#pragma unroll
    for (int i = 0; i < 9; i++) {            // W chunk: 72x128 = 2304 float4
      int idx = t + 256 * i;
      int rr = idx >> 5, kk = (idx & 31) << 2;
      *(float4*)&Ws[rr][kk] = *(const float4*)&Wi[(size_t)rr * INDIM + kc * 128 + kk];
    }
    __syncthreads();
    const int kb = ks * 64;
#pragma unroll 4
    for (int kq = 0; kq < 16; kq++) {
      const float4 xv = *(const float4*)&xs[r2][kb + kq * 4];
#pragma unroll
      for (int j = 0; j < 9; j++) {
        const float4 wv = *(const float4*)&Ws[u + 8 * j][kb + kq * 4];
        acc[j] = fmaf(xv.x, wv.x, fmaf(xv.y, wv.y, fmaf(xv.z, wv.z, fmaf(xv.w, wv.w, acc[j]))));
      }
    }
  }
  // combine k-halves
#pragma unroll
  for (int j = 0; j < 9; j++) acc[j] += __shfl_xor(acc[j], 8);

  // add bias, LN over 72
  float yv[9];
  float ps = 0.f, pq = 0.f;
#pragma unroll
  for (int j = 0; j < 9; j++) {
    const int o = u + 8 * j;
    yv[j] = acc[j] + bi[o];
    ps += yv[j]; pq += yv[j] * yv[j];
  }
#pragma unroll
  for (int m = 1; m < 8; m <<= 1) { ps += __shfl_xor(ps, m); pq += __shfl_xor(pq, m); }
  const float mean = ps * (1.f / 72.f);
  const float var  = pq * (1.f / 72.f) - mean * mean;
  const float rstd = rsqrtf(var + 1e-5f);
#pragma unroll
  for (int j = 0; j < 9; j++) {
    const int o = u + 8 * j;
    const float z = gelu_exact((yv[j] - mean) * rstd * gi[o] + bbi[o]);
    if (ks == 0) zs[r2][o] = z;
  }
  __syncthreads();
  {
    const int kt = t & 15;
    for (int e = kt; e < 24; e += 16)
      zb[r2][e] = (zs[r2][3 * e] + zs[r2][3 * e + 1] + zs[r2][3 * e + 2]) * (1.f / 3.f);
  }
  __syncthreads();
  {
    const int kt = t & 15;
    float qnp = 0.f;
    for (int d = kt; d < 24; d += 16) {
      float qd = 0.f;
#pragma unroll
      for (int e = 0; e < 24; e++) qd = fmaf(zb[r2][e], ricci[e * 24 + d], qd);
      qvec[(size_t)(row0 + r2) * DM + d] = qd;
      qnp = fmaf(qd, qd, qnp);
    }
#pragma unroll
    for (int m = 1; m < 16; m <<= 1) qnp += __shfl_xor(qnp, m, 16);
    if (kt == 0) qnorm[row0 + r2] = qnp;
  }
}

// ---------------------------------------------------------------------------
// K2: key norms + quantum-phase means
// ---------------------------------------------------------------------------
__global__ __launch_bounds__(256) void k2_prep(
    const float* __restrict__ keys, const float* __restrict__ qp,
    float* __restrict__ kn, float* __restrict__ pm)
{
  const int m = blockIdx.x * 256 + threadIdx.x;
  float s = 0.f;
#pragma unroll
  for (int d = 0; d < DM; d++) { const float v = keys[(size_t)m * DM + d]; s = fmaf(v, v, s); }
  kn[m] = s;
  float p = 0.f;
#pragma unroll
  for (int q = 0; q < 8; q++) p += tanhf(qp[(size_t)m * 8 + q]);
  pm[m] = p * 0.125f;
}

// ---------------------------------------------------------------------------
// K3: distances + exact top-32 + softmax + gain.
// block: 256 threads, 16 rows (4 rows per wave). Two-pass group-min scheme.
// ---------------------------------------------------------------------------
__global__ __launch_bounds__(256) void k3_topk(
    const float* __restrict__ qvec, const float* __restrict__ qnorm,
    const float* __restrict__ keys, const float* __restrict__ kn,
    const float* __restrict__ fw,  const float* __restrict__ pm,
    float* __restrict__ w_out, int* __restrict__ itop_out, float* __restrict__ gain_out)
{
  __shared__ float qs[16][25];
  __shared__ float qns[16];
  __shared__ float kch[DM][256];
  __shared__ float knch[256];
  __shared__ float gmins[16][64];
  __shared__ float Ts[16];
  __shared__ unsigned flg[16][64];
  __shared__ unsigned candV[16][CAND];
  __shared__ unsigned candI[16][CAND];
  __shared__ int cnt[16];
  __shared__ float wV[16][KSEL];
  __shared__ int   wI[16][KSEL];

  const int t = threadIdx.x;
  const int row0 = blockIdx.x * 16;
  const int wv = t >> 6, lane = t & 63, wv4 = wv * 4;

  for (int idx = t; idx < 16 * DM; idx += 256) qs[idx / DM][idx % DM] = qvec[(size_t)row0 * DM + idx];
  if (t < 16) { qns[t] = qnorm[row0 + t]; cnt[t] = 0; }
  __syncthreads();

  float ql0[DM], ql1[DM], ql2[DM], ql3[DM];
#pragma unroll
  for (int d = 0; d < DM; d++) {
    ql0[d] = qs[wv4 + 0][d]; ql1[d] = qs[wv4 + 1][d];
    ql2[d] = qs[wv4 + 2][d]; ql3[d] = qs[wv4 + 3][d];
  }
  const float qn0 = qns[wv4 + 0], qn1 = qns[wv4 + 1], qn2 = qns[wv4 + 2], qn3 = qns[wv4 + 3];

  // ---- pass A: group minima (64 groups of 128 keys per row) ----
  for (int c = 0; c < 32; c++) {
    __syncthreads();
    {
      const float* kp = &keys[(size_t)(c * 256 + t) * DM];
      float kv[DM];
#pragma unroll
      for (int d = 0; d < DM; d += 4) {
        const float4 v = *(const float4*)(kp + d);
        kv[d] = v.x; kv[d + 1] = v.y; kv[d + 2] = v.z; kv[d + 3] = v.w;
      }
#pragma unroll
      for (int d = 0; d < DM; d++) kch[d][t] = kv[d];
      knch[t] = kn[c * 256 + t];
    }
    __syncthreads();
#pragma unroll
    for (int half = 0; half < 2; half++) {
      float g0 = 1e30f, g1 = 1e30f, g2 = 1e30f, g3 = 1e30f;
#pragma unroll
      for (int il = 0; il < 2; il++) {
        const int kk = (half * 2 + il) * 64 + lane;
        const float knn = knch[kk];
        float d0 = 0.f, d1 = 0.f, d2_ = 0.f, d3 = 0.f;
#pragma unroll
        for (int d = 0; d < DM; d++) {
          const float kvd = kch[d][kk];
          d0 = fmaf(kvd, ql0[d], d0); d1 = fmaf(kvd, ql1[d], d1);
          d2_ = fmaf(kvd, ql2[d], d2_); d3 = fmaf(kvd, ql3[d], d3);
        }
        g0 = fminf(g0, fmaf(-2.f, d0, qn0 + knn));
        g1 = fminf(g1, fmaf(-2.f, d1, qn1 + knn));
        g2 = fminf(g2, fmaf(-2.f, d2_, qn2 + knn));
        g3 = fminf(g3, fmaf(-2.f, d3, qn3 + knn));
      }
#pragma unroll
      for (int m = 1; m < 64; m <<= 1) {
        g0 = fminf(g0, __shfl_xor(g0, m)); g1 = fminf(g1, __shfl_xor(g1, m));
        g2 = fminf(g2, __shfl_xor(g2, m)); g3 = fminf(g3, __shfl_xor(g3, m));
      }
      if (lane == 0) {
        gmins[wv4 + 0][c * 2 + half] = g0; gmins[wv4 + 1][c * 2 + half] = g1;
        gmins[wv4 + 2][c * 2 + half] = g2; gmins[wv4 + 3][c * 2 + half] = g3;
      }
    }
  }
  __syncthreads();

  // ---- threshold T = 32nd smallest group-min per row ----
  {
    const int r = t >> 4, kt = t & 15;
    const float c0 = gmins[r][kt * 4 + 0], c1 = gmins[r][kt * 4 + 1];
    const float c2 = gmins[r][kt * 4 + 2], c3 = gmins[r][kt * 4 + 3];
    int r0 = 0, r1 = 0, r2_ = 0, r3 = 0;
    for (int g = 0; g < 64; g++) {
      const float gv = gmins[r][g];
      r0 += (gv < c0); r1 += (gv < c1); r2_ += (gv < c2); r3 += (gv < c3);
    }
    if (r0 == 31) Ts[r] = c0;
    if (r1 == 31) Ts[r] = c1;
    if (r2_ == 31) Ts[r] = c2;
    if (r3 == 31) Ts[r] = c3;
  }
  __syncthreads();
  {
    const int r = t >> 4, kt = t & 15;
    const float T = Ts[r];
    const float Tm = T + fabsf(T) * 1e-6f + 1e-20f;
#pragma unroll
    for (int a = 0; a < 4; a++) flg[r][kt * 4 + a] = (gmins[r][kt * 4 + a] <= Tm) ? 1u : 0u;
  }
  for (int idx = t; idx < 16 * KSEL; idx += 256) { wV[idx >> 5][idx & 31] = 1e30f; wI[idx >> 5][idx & 31] = 0; }
  __syncthreads();

  const float TmA0 = Ts[wv4 + 0] + fabsf(Ts[wv4 + 0]) * 1e-6f + 1e-20f;
  const float TmA1 = Ts[wv4 + 1] + fabsf(Ts[wv4 + 1]) * 1e-6f + 1e-20f;
  const float TmA2 = Ts[wv4 + 2] + fabsf(Ts[wv4 + 2]) * 1e-6f + 1e-20f;
  const float TmA3 = Ts[wv4 + 3] + fabsf(Ts[wv4 + 3]) * 1e-6f + 1e-20f;

  // ---- pass B: recompute live groups, compact candidates <= Tm ----
  for (int c = 0; c < 32; c++) {
    __syncthreads();
    {
      const float* kp = &keys[(size_t)(c * 256 + t) * DM];
      float kv[DM];
#pragma unroll
      for (int d = 0; d < DM; d += 4) {
        const float4 v = *(const float4*)(kp + d);
        kv[d] = v.x; kv[d + 1] = v.y; kv[d + 2] = v.z; kv[d + 3] = v.w;
      }
#pragma unroll
      for (int d = 0; d < DM; d++) kch[d][t] = kv[d];
      knch[t] = kn[c * 256 + t];
    }
    __syncthreads();
#pragma unroll
    for (int half = 0; half < 2; half++) {
      const int g = c * 2 + half;
      const unsigned f0 = flg[wv4 + 0][g], f1 = flg[wv4 + 1][g];
      const unsigned f2 = flg[wv4 + 2][g], f3 = flg[wv4 + 3][g];
#pragma unroll
      for (int il = 0; il < 2; il++) {
        const int kk = (half * 2 + il) * 64 + lane;
        const float knn = knch[kk];
        if (f0) {
          float dt = 0.f;
#pragma unroll
          for (int d = 0; d < DM; d++) dt = fmaf(kch[d][kk], ql0[d], dt);
          const float d2v = fmaf(-2.f, dt, qn0 + knn);
          if (d2v <= TmA0) {
            const int pos = atomicAdd(&cnt[wv4 + 0], 1);
            if (pos < CAND) { candV[wv4 + 0][pos] = __float_as_uint(fmaxf(d2v, 0.f)); candI[wv4 + 0][pos] = c * 256 + kk; }
          }
        }
        if (f1) {
          float dt = 0.f;
#pragma unroll
          for (int d = 0; d < DM; d++) dt = fmaf(kch[d][kk], ql1[d], dt);
          const float d2v = fmaf(-2.f, dt, qn1 + knn);
          if (d2v <= TmA1) {
            const int pos = atomicAdd(&cnt[wv4 + 1], 1);
            if (pos < CAND) { candV[wv4 + 1][pos] = __float_as_uint(fmaxf(d2v, 0.f)); candI[wv4 + 1][pos] = c * 256 + kk; }
          }
        }
        if (f2) {
          float dt = 0.f;
#pragma unroll
          for (int d = 0; d < DM; d++) dt = fmaf(kch[d][kk], ql2[d], dt);
          const float d2v = fmaf(-2.f, dt, qn2 + knn);
          if (d2v <= TmA2) {
            const int pos = atomicAdd(&cnt[wv4 + 2], 1);
            if (pos < CAND) { candV[wv4 + 2][pos] = __float_as_uint(fmaxf(d2v, 0.f)); candI[wv4 + 2][pos] = c * 256 + kk; }
          }
        }
        if (f3) {
          float dt = 0.f;
#pragma unroll
          for (int d = 0; d < DM; d++) dt = fmaf(kch[d][kk], ql3[d], dt);
          const float d2v = fmaf(-2.f, dt, qn3 + knn);
          if (d2v <= TmA3) {
            const int pos = atomicAdd(&cnt[wv4 + 3], 1);
            if (pos < CAND) { candV[wv4 + 3][pos] = __float_as_uint(fmaxf(d2v, 0.f)); candI[wv4 + 3][pos] = c * 256 + kk; }
          }
        }
      }
    }
  }
  __syncthreads();

  // ---- exact rank-select top-32 among candidates ----
  {
    const int r = t >> 4, kt = t & 15;
    const int C = min(cnt[r], CAND);
    for (int ci = kt; ci < C; ci += 16) {
      const unsigned v = candV[r][ci];
      const unsigned key = candI[r][ci];
      int rk = 0;
      for (int j = 0; j < C; j++) {
        const unsigned vj = candV[r][j];
        rk += (vj < v) || (vj == v && candI[r][j] < key);
      }
      if (rk < KSEL) { wV[r][rk] = __uint_as_float(v); wI[r][rk] = (int)key; }
    }
  }
  __syncthreads();

  // ---- softmax over -dist, gain ----
  float sc;
  {
    const float f0 = fw[0], f1 = fw[1], f2 = fw[2], f3 = fw[3];
    const float mx = fmaxf(fmaxf(f0, f1), fmaxf(f2, f3));
    const float e0 = expf(f0 - mx), e1 = expf(f1 - mx), e2 = expf(f2 - mx), e3 = expf(f3 - mx);
    sc = (e0 + 0.5f * e1 + 0.25f * e2 + 0.125f * e3) / (e0 + e1 + e2 + e3);
  }
  {
    const int r = t >> 4, kt = t & 15;
    const float dA = sqrtf(wV[r][kt]) * sc;
    const float dB = sqrtf(wV[r][kt + 16]) * sc;
    float mn = fminf(dA, dB);
#pragma unroll
    for (int m = 1; m < 16; m <<= 1) mn = fminf(mn, __shfl_xor(mn, m, 16));
    const float eA = expf(mn - dA), eB = expf(mn - dB);
    float s = eA + eB;
#pragma unroll
    for (int m = 1; m < 16; m <<= 1) s += __shfl_xor(s, m, 16);
    const float w0 = eA / s, w1 = eB / s;
    const int k0 = wI[r][kt], k1 = wI[r][kt + 16];
    float gp = w0 * pm[k0] + w1 * pm[k1];
#pragma unroll
    for (int m = 1; m < 16; m <<= 1) gp += __shfl_xor(gp, m, 16);
    const size_t row = (size_t)(row0 + r);
    w_out[row * KSEL + kt] = w0;      w_out[row * KSEL + kt + 16] = w1;
    itop_out[row * KSEL + kt] = k0;   itop_out[row * KSEL + kt + 16] = k1;
    if (kt == 0) gain_out[row] = 1.f + 0.02f * gp;
  }
}

// ---------------------------------------------------------------------------
// K4: p = x@key_phase_W.T + b ; Kf = FFT(e^{i 2pi sigmoid(p)}) * e^{i ek}
// block: 256 threads, 16 rows. GEMM (768->256) then radix-2 FFT-256 in LDS.
// ---------------------------------------------------------------------------
__global__ __launch_bounds__(256) void k4_phase(
    const float* __restrict__ x, const float* __restrict__ Wp,
    const float* __restrict__ bp, const float* __restrict__ ek,
    float* __restrict__ kf_re, float* __restrict__ kf_im)
{
  __shared__ float xs[16][36];
  __shared__ float Ws[HN][36];
  __shared__ float sre[16][260];
  __shared__ float sim_[16][260];
  __shared__ float twc[HN], tws[HN];
  const int t = threadIdx.x;
  const int row0 = blockIdx.x * 16;
  {
    const float a = (float)t * (TWO_PI_F / 256.f);
    twc[t] = cosf(a); tws[t] = sinf(a);
  }
  const int r = t >> 4, cg = t & 15;
  float acc[16];
#pragma unroll
  for (int j = 0; j < 16; j++) acc[j] = bp[cg + 16 * j];

  for (int kc = 0; kc < 24; kc++) {
    __syncthreads();
    if (t < 128) {
      const int rr = t >> 3, kk = (t & 7) << 2;
      *(float4*)&xs[rr][kk] = *(const float4*)&x[(size_t)(row0 + rr) * INDIM + kc * 32 + kk];
    }
#pragma unroll
    for (int i = 0; i < 8; i++) {
      const int idx = t + 256 * i;
      const int rr = idx >> 3, kk = (idx & 7) << 2;
      *(float4*)&Ws[rr][kk] = *(const float4*)&Wp[(size_t)rr * INDIM + kc * 32 + kk];
    }
    __syncthreads();
#pragma unroll
    for (int kq = 0; kq < 8; kq++) {
      const float4 xv = *(const float4*)&xs[r][kq * 4];
#pragma unroll
      for (int j = 0; j < 16; j++) {
        const float4 wv = *(const float4*)&Ws[cg + 16 * j][kq * 4];
        acc[j] = fmaf(xv.x, wv.x, fmaf(xv.y, wv.y, fmaf(xv.z, wv.z, fmaf(xv.w, wv.w, acc[j]))));
      }
    }
  }
  __syncthreads();
#pragma unroll
  for (int j = 0; j < 16; j++) {
    const int c = cg + 16 * j;
    const float sg = 1.f / (1.f + expf(-acc[j]));
    float sn, cs;
    __sincosf(TWO_PI_F * sg, &sn, &cs);
    const int hb = __brev((unsigned)c) >> 24;
    sre[r][hb] = cs; sim_[r][hb] = sn;
  }
  __syncthreads();
  const int t16 = t & 15;
  for (int s = 0; s < 8; s++) {
    const int half = 1 << s;
#pragma unroll
    for (int p = 0; p < 8; p++) {
      const int bi = t16 + 16 * p;
      const int jj = bi & (half - 1);
      const int base = (bi >> s) << (s + 1);
      const int i0 = base + jj, i1 = i0 + half;
      const int tw = jj << (7 - s);
      const float wr = twc[tw], wi = -tws[tw];
      const float ar = sre[r][i0], ai = sim_[r][i0];
      const float br = sre[r][i1], b2 = sim_[r][i1];
      const float tr = wr * br - wi * b2, ti = wr * b2 + wi * br;
      sre[r][i0] = ar + tr; sim_[r][i0] = ai + ti;
      sre[r][i1] = ar - tr; sim_[r][i1] = ai - ti;
    }
    __syncthreads();
  }
#pragma unroll
  for (int p = 0; p < 16; p++) {
    const int h = t16 + 16 * p;
    float sn, cs;
    __sincosf(ek[h], &sn, &cs);
    const float xr = sre[r][h], xi = sim_[r][h];
    const size_t o = (size_t)(row0 + r) * HN + h;
    kf_re[o] = xr * cs - xi * sn;
    kf_im[o] = xr * sn + xi * cs;
  }
}

// ---------------------------------------------------------------------------
// K5: Hmix gather + conj(Kf)*Hmix ; IFFT-256 ; readout GEMM (512->72)
// ---------------------------------------------------------------------------
__global__ __launch_bounds__(256) void k5_holo(
    const float* __restrict__ holo_re, const float* __restrict__ holo_im,
    const float* __restrict__ kf_re, const float* __restrict__ kf_im,
    const float* __restrict__ w_ws, const int* __restrict__ itop_ws,
    const float* __restrict__ RW, const float* __restrict__ rb,
    float* __restrict__ triplet)
{
  __shared__ float wsm[16][KSEL];
  __shared__ int   ism[16][KSEL];
  __shared__ float sre[16][260];
  __shared__ float sim_[16][260];
  __shared__ float twc[HN], tws[HN];
  const int t = threadIdx.x;
  const int row0 = blockIdx.x * 16;
  {
    const float a = (float)t * (TWO_PI_F / 256.f);
    twc[t] = cosf(a); tws[t] = sinf(a);
  }
  for (int idx = t; idx < 16 * KSEL; idx += 256) {
    wsm[idx >> 5][idx & 31] = w_ws[(size_t)row0 * KSEL + idx];
    ism[idx >> 5][idx & 31] = itop_ws[(size_t)row0 * KSEL + idx];
  }
  __syncthreads();
  {
    const int h = t;
    const int hb = __brev((unsigned)h) >> 24;
    for (int r = 0; r < 16; r++) {
      float hr = 0.f, hi = 0.f;
#pragma unroll 8
      for (int k2 = 0; k2 < KSEL; k2++) {
        const int m = ism[r][k2];
        const float wk = wsm[r][k2];
        hr = fmaf(wk, holo_re[(size_t)m * HN + h], hr);
        hi = fmaf(wk, holo_im[(size_t)m * HN + h], hi);
      }
      const size_t o = (size_t)(row0 + r) * HN + h;
      const float kr = kf_re[o], ki = kf_im[o];
      sre[r][hb] = kr * hr + ki * hi;   // conj(Kf) * Hmix
      sim_[r][hb] = kr * hi - ki * hr;
    }
  }
  __syncthreads();
  const int r = t >> 4, t16 = t & 15;
  for (int s = 0; s < 8; s++) {
    const int half = 1 << s;
#pragma unroll
    for (int p = 0; p < 8; p++) {
      const int bi = t16 + 16 * p;
      const int jj = bi & (half - 1);
      const int base = (bi >> s) << (s + 1);
      const int i0 = base + jj, i1 = i0 + half;
      const int tw = jj << (7 - s);
      const float wr = twc[tw], wi = tws[tw];   // conj twiddle for inverse
      const float ar = sre[r][i0], ai = sim_[r][i0];
      const float br = sre[r][i1], b2 = sim_[r][i1];
      const float tr = wr * br - wi * b2, ti = wr * b2 + wi * br;
      sre[r][i0] = ar + tr; sim_[r][i0] = ai + ti;
      sre[r][i1] = ar - tr; sim_[r][i1] = ai - ti;
    }
    __syncthreads();
  }
  // readout: triplet[o] = rb[o] + (1/256) * sum_h (re*RW[o][h] + im*RW[o][256+h])
  float dac[5] = {0.f, 0.f, 0.f, 0.f, 0.f};
  for (int h4 = 0; h4 < 256; h4 += 4) {
    const float4 vr = *(const float4*)&sre[r][h4];
#pragma unroll
    for (int u = 0; u < 5; u++) {
      const int o = t16 + 16 * u;
      if (o < TD) {
        const float4 wv = *(const float4*)&RW[(size_t)o * 512 + h4];
        dac[u] = fmaf(vr.x, wv.x, fmaf(vr.y, wv.y, fmaf(vr.z, wv.z, fmaf(vr.w, wv.w, dac[u]))));
      }
    }
  }
  for (int h4 = 0; h4 < 256; h4 += 4) {
    const float4 vi = *(const float4*)&sim_[r][h4];
#pragma unroll
    for (int u = 0; u < 5; u++) {
      const int o = t16 + 16 * u;
      if (o < TD) {
        const float4 wv = *(const float4*)&RW[(size_t)o * 512 + 256 + h4];
        dac[u] = fmaf(vi.x, wv.x, fmaf(vi.y, wv.y, fmaf(vi.z, wv.z, fmaf(vi.w, wv.w, dac[u]))));
      }
    }
  }
#pragma unroll
  for (int u = 0; u < 5; u++) {
    const int o = t16 + 16 * u;
    if (o < TD) triplet[(size_t)(row0 + r) * TD + o] = rb[o] + dac[u] * (1.f / 256.f);
  }
}

// ---------------------------------------------------------------------------
// K6: out = gelu(LN(triplet@W_out.T + b_out)) * gain
// ---------------------------------------------------------------------------
__global__ __launch_bounds__(256) void k6_out(
    const float* __restrict__ triplet, const float* __restrict__ Wo,
    const float* __restrict__ bo, const float* __restrict__ go,
    const float* __restrict__ bbo, const float* __restrict__ gain,
    float* __restrict__ out)
{
  __shared__ float ts[16][76];
  __shared__ float ys[16][772];
  const int t = threadIdx.x;
  const int row0 = blockIdx.x * 16;
  for (int idx = t; idx < 16 * TD; idx += 256) ts[idx / TD][idx % TD] = triplet[(size_t)row0 * TD + idx];
  __syncthreads();
  float acc[16][3];
#pragma unroll
  for (int rr = 0; rr < 16; rr++) { acc[rr][0] = 0.f; acc[rr][1] = 0.f; acc[rr][2] = 0.f; }
  for (int e = 0; e < TD; e++) {
    float wv[3];
#pragma unroll
    for (int j = 0; j < 3; j++) wv[j] = Wo[(size_t)(t + 256 * j) * TD + e];
#pragma unroll
    for (int rr = 0; rr < 16; rr++) {
      const float tv = ts[rr][e];
      acc[rr][0] = fmaf(tv, wv[0], acc[rr][0]);
      acc[rr][1] = fmaf(tv, wv[1], acc[rr][1]);
      acc[rr][2] = fmaf(tv, wv[2], acc[rr][2]);
    }
  }
  {
    const float b0 = bo[t], b1 = bo[t + 256], b2 = bo[t + 512];
#pragma unroll
    for (int rr = 0; rr < 16; rr++) {
      ys[rr][t] = acc[rr][0] + b0;
      ys[rr][t + 256] = acc[rr][1] + b1;
      ys[rr][t + 512] = acc[rr][2] + b2;
    }
  }
  __syncthreads();
  const int r = t >> 4, kt = t & 15;
  float s = 0.f, sq = 0.f;
  for (int u = 0; u < 48; u++) {
    const float v = ys[r][kt + 16 * u];
    s += v; sq = fmaf(v, v, sq);
  }
#pragma unroll
  for (int m = 1; m < 16; m <<= 1) { s += __shfl_xor(s, m, 16); sq += __shfl_xor(sq, m, 16); }
  const float mean = s * (1.f / 768.f);
  const float var  = sq * (1.f / 768.f) - mean * mean;
  const float rstd = rsqrtf(var + 1e-5f);
  const float gn = gain[row0 + r];
  for (int u = 0; u < 48; u++) {
    const int e = kt + 16 * u;
    const float v = (ys[r][e] - mean) * rstd * go[e] + bbo[e];
    out[(size_t)(row0 + r) * INDIM + e] = gelu_exact(v) * gn;
  }
}

// ---------------------------------------------------------------------------
extern "C" void kernel_launch(void* const* d_in, const int* in_sizes, int n_in,
                              void* d_out, int out_size, void* d_ws, size_t ws_size,
                              hipStream_t stream)
{
  (void)in_sizes; (void)n_in; (void)out_size; (void)ws_size;
  const float* x     = (const float*)d_in[0];
  const float* Wi    = (const float*)d_in[1];
  const float* bi    = (const float*)d_in[2];
  const float* gi    = (const float*)d_in[3];
  const float* bbi   = (const float*)d_in[4];
  const float* ricci = (const float*)d_in[5];
  const float* fw    = (const float*)d_in[6];
  const float* keys  = (const float*)d_in[7];
  const float* Wp    = (const float*)d_in[8];
  const float* bp    = (const float*)d_in[9];
  const float* ek    = (const float*)d_in[10];
  const float* hre   = (const float*)d_in[11];
  const float* him   = (const float*)d_in[12];
  const float* RW    = (const float*)d_in[13];
  const float* rb    = (const float*)d_in[14];
  const float* Wo    = (const float*)d_in[15];
  const float* bo    = (const float*)d_in[16];
  const float* go    = (const float*)d_in[17];
  const float* bbo   = (const float*)d_in[18];
  const float* qp    = (const float*)d_in[19];
  float* out = (float*)d_out;

  char* ws = (char*)d_ws;
  float* qvec    = (float*)(ws + 0);
  float* qnorm   = (float*)(ws + 786432);
  float* kn      = (float*)(ws + 819200);
  float* pm      = (float*)(ws + 851968);
  float* gain    = (float*)(ws + 884736);
  float* w_ws    = (float*)(ws + 917504);
  int*   itop    = (int*)  (ws + 1966080);
  float* triplet = (float*)(ws + 3014656);
  float* kf_re   = (float*)(ws + 5373952);
  float* kf_im   = (float*)(ws + 13762560);
  // total workspace use: 22151168 bytes

  k1_encode<<<dim3(NROWS / 16), dim3(256), 0, stream>>>(x, Wi, bi, gi, bbi, ricci, qvec, qnorm);
  k2_prep<<<dim3(MKEYS / 256), dim3(256), 0, stream>>>(keys, qp, kn, pm);
  k4_phase<<<dim3(NROWS / 16), dim3(256), 0, stream>>>(x, Wp, bp, ek, kf_re, kf_im);
  k3_topk<<<dim3(NROWS / 16), dim3(256), 0, stream>>>(qvec, qnorm, keys, kn, fw, pm, w_ws, itop, gain);
  k5_holo<<<dim3(NROWS / 16), dim3(256), 0, stream>>>(hre, him, kf_re, kf_im, w_ws, itop, RW, rb, triplet);
  k6_out<<<dim3(NROWS / 16), dim3(256), 0, stream>>>(triplet, Wo, bo, go, bbo, gain, out);
}